// Round 5
// baseline (270.883 us; speedup 1.0000x reference)
//
#include <hip/hip_runtime.h>
#include <math.h>

// Problem constants (from reference)
#define NB 32      // batch
#define NN 8192    // neighbors
#define DD 384     // feature dim
#define LL 128     // latent dim
#define CHUNKS 32  // blocks per batch in stream kernel
#define RPB 256    // rows per block (NN/CHUNKS)
#define NWAVES 4   // waves per block
#define RPW 64     // rows per wave

// ---------------------------------------------------------------------------
// Kernel A: per-batch q = target@Wq+bq (internal), then u = scale*(Wk@q),
// c = scale*(bk.q). All loads coalesced (Wk via per-row float2 + butterfly).
// Block 0 probes mask dtype and zeroes the per-batch arrival counters.
// ---------------------------------------------------------------------------
__global__ __launch_bounds__(384) void ga_prep(
    const float* __restrict__ target,
    const float* __restrict__ Wq, const float* __restrict__ bq,
    const float* __restrict__ Wk, const float* __restrict__ bk,
    const void* __restrict__ mask,
    float* __restrict__ u, float* __restrict__ c, int* __restrict__ flag,
    int* __restrict__ counters)
{
    const int b = blockIdx.x;   // 32 blocks
    const int t = threadIdx.x;  // 384 threads
    const int w = t >> 6;       // wave 0..5
    const int l = t & 63;       // lane

    __shared__ float tgt[DD];
    __shared__ __align__(16) float qs[LL];
    __shared__ float qp[3][LL];
    __shared__ int s_notint, s_notflt;

    if (b == 0 && t == 0) { s_notint = 0; s_notflt = 0; }
    if (b == 0 && t < NB) counters[t] = 0;   // reset arrival counters each call
    tgt[t] = target[b * DD + t];
    __syncthreads();

    // Mask dtype probe (block 0 only): int32 {0,1} vs float32 vs bytes
    if (b == 0 && t < 256) {
        unsigned v = ((const unsigned*)mask)[t];
        if (v > 1u) s_notint = 1;                       // benign race, all write 1
        if (v != 0u && v != 0x3F800000u) s_notflt = 1;
    }

    // q[ll] = bq[ll] + sum_d tgt[d]*Wq[d*128+ll], split d into 3 segments
    const int ll = t & (LL - 1);
    const int seg = t >> 7;  // 0..2
    float acc = 0.f;
#pragma unroll 4
    for (int i = 0; i < 128; ++i) {
        int d = seg * 128 + i;
        acc += tgt[d] * Wq[d * LL + ll];  // coalesced across ll
    }
    qp[seg][ll] = acc;
    __syncthreads();
    if (t < LL) qs[t] = qp[0][t] + qp[1][t] + qp[2][t] + bq[t];
    __syncthreads();

    const float scale = 0.051031036307982884f;  // 1/sqrt(384)

    // c[b] = scale * dot(bk, qs): wave 0, lane-parallel float2 + butterfly
    if (w == 0) {
        const float2 bk2 = *(const float2*)&bk[2 * l];
        const float2 q2  = *(const float2*)&qs[2 * l];
        float part = bk2.x * q2.x + bk2.y * q2.y;
#pragma unroll
        for (int off = 32; off; off >>= 1) part += __shfl_xor(part, off, 64);
        if (l == 0) c[b] = part * scale;
    }

    // u[d] = scale * sum_l Wk[d*128+l]*qs[l]; wave w handles rows w*64..w*64+63
    // coalesced: lane l reads float2 at Wk[d*128 + 2l] (512 B per wave instr)
    const float2 q2 = *(const float2*)&qs[2 * l];
    for (int r = 0; r < 64; ++r) {
        const int d = w * 64 + r;
        const float2 wk = *(const float2*)&Wk[d * LL + 2 * l];
        float part = wk.x * q2.x + wk.y * q2.y;
#pragma unroll
        for (int off = 32; off; off >>= 1) part += __shfl_xor(part, off, 64);
        if (l == 0) u[b * DD + d] = part * scale;
    }

    __syncthreads();
    if (b == 0 && t == 0) *flag = s_notint ? (s_notflt ? 2 : 1) : 0;
}

// ---------------------------------------------------------------------------
// Kernel B: stream h (mask-skip, r2-identical main loop) + FUSED FINISH via
// last-block-done: each block publishes its (m,s,a[384]) partial, fences,
// atomically bumps its batch counter; the 32nd arrival does the per-batch
// softmax-merge + Wv matvec + MLP inline.
// ---------------------------------------------------------------------------

#define GA_LOAD(j) \
    const int r##j = (base + j < cnt) ? wlist[wave][base + j] : 0; \
    const float* row##j = hb + (size_t)r##j * DD; \
    const float4 xa##j = *(const float4*)(row##j + 4 * lane); \
    const float2 xb##j = *(const float2*)(row##j + 256 + 2 * lane);

#define GA_DOT(j) \
    float d##j = xa##j.x * ua.x + xa##j.y * ua.y + xa##j.z * ua.z + \
                 xa##j.w * ua.w + xb##j.x * ub2.x + xb##j.y * ub2.y;

__global__ __launch_bounds__(256, 4) void ga_stream(
    const float* __restrict__ h, const void* __restrict__ mask,
    const float* __restrict__ u, const float* __restrict__ c,
    const int* __restrict__ flag,
    float* __restrict__ pm, float* __restrict__ ps, float* __restrict__ pa,
    int* __restrict__ counters,
    const float* __restrict__ target,
    const float* __restrict__ Wv, const float* __restrict__ bv,
    const float* __restrict__ W1, const float* __restrict__ b1,
    const float* __restrict__ W2, const float* __restrict__ b2,
    float* __restrict__ out)
{
    const int blk = blockIdx.x;           // 1024 blocks
    const int b = blk >> 5;               // batch
    const int chunk = blk & (CHUNKS - 1);
    const int wave = threadIdx.x >> 6;
    const int lane = threadIdx.x & 63;
    const int t = threadIdx.x;

    // u fragment: float4 over elems [0,256), float2 over [256,384)
    const float* ubase = u + b * DD;
    const float4 ua  = *(const float4*)(ubase + 4 * lane);
    const float2 ub2 = *(const float2*)(ubase + 256 + 2 * lane);
    const float cc = c[b];

    const int n0 = chunk * RPB + wave * RPW;
    const size_t rowbase = (size_t)b * NN + n0;
    const float* hb = h + rowbase * DD;

    // Gather this wave's 64 mask bits -> ballot, compact indices into LDS
    const int fm = *flag;
    int myMask;
    const size_t mi = rowbase + lane;
    if (fm == 0)      myMask = ((const int*)mask)[mi] != 0;
    else if (fm == 1) myMask = ((const unsigned*)mask)[mi] != 0u;
    else              myMask = ((const unsigned char*)mask)[mi] != 0;
    const unsigned long long mbits = __ballot(myMask);
    const int cnt = __popcll(mbits);
    const int pos = __popcll(mbits & ((1ull << lane) - 1ull));

    __shared__ int wlist[NWAVES][64];
    __shared__ float lm[NWAVES], lss[NWAVES];
    __shared__ float la[NWAVES][DD];

    if (myMask) wlist[wave][pos] = lane;   // wave-synchronous, no barrier needed

    float m = -INFINITY, s = 0.f;
    float a0 = 0.f, a1 = 0.f, a2 = 0.f, a3 = 0.f, a4 = 0.f, a5 = 0.f;

    for (int base = 0; base < cnt; base += 8) {
        GA_LOAD(0) GA_LOAD(1) GA_LOAD(2) GA_LOAD(3)
        GA_LOAD(4) GA_LOAD(5) GA_LOAD(6) GA_LOAD(7)

        GA_DOT(0) GA_DOT(1) GA_DOT(2) GA_DOT(3)
        GA_DOT(4) GA_DOT(5) GA_DOT(6) GA_DOT(7)

#pragma unroll
        for (int off = 32; off; off >>= 1) {
            d0 += __shfl_xor(d0, off, 64);
            d1 += __shfl_xor(d1, off, 64);
            d2 += __shfl_xor(d2, off, 64);
            d3 += __shfl_xor(d3, off, 64);
            d4 += __shfl_xor(d4, off, 64);
            d5 += __shfl_xor(d5, off, 64);
            d6 += __shfl_xor(d6, off, 64);
            d7 += __shfl_xor(d7, off, 64);
        }

        const int nv = cnt - base;  // >= 1
        const float s0v = d0 + cc;
        const float s1v = d1 + cc, s2v = d2 + cc, s3v = d3 + cc;
        const float s4v = d4 + cc, s5v = d5 + cc, s6v = d6 + cc, s7v = d7 + cc;

        const float t1 = (1 < nv) ? s1v : -INFINITY;
        const float t2 = (2 < nv) ? s2v : -INFINITY;
        const float t3 = (3 < nv) ? s3v : -INFINITY;
        const float t4 = (4 < nv) ? s4v : -INFINITY;
        const float t5 = (5 < nv) ? s5v : -INFINITY;
        const float t6 = (6 < nv) ? s6v : -INFINITY;
        const float t7 = (7 < nv) ? s7v : -INFINITY;
        const float M8 = fmaxf(fmaxf(fmaxf(s0v, t1), fmaxf(t2, t3)),
                               fmaxf(fmaxf(t4, t5), fmaxf(t6, t7)));
        const float mn = fmaxf(m, M8);
        const float f = __expf(m - mn);  // first iter: exp(-inf)=0, s/a are 0 anyway
        m = mn;
        s *= f;
        a0 *= f; a1 *= f; a2 *= f; a3 *= f; a4 *= f; a5 *= f;

        const float p0 = __expf(s0v - m);
        const float p1 = (1 < nv) ? __expf(s1v - m) : 0.f;
        const float p2 = (2 < nv) ? __expf(s2v - m) : 0.f;
        const float p3 = (3 < nv) ? __expf(s3v - m) : 0.f;
        const float p4 = (4 < nv) ? __expf(s4v - m) : 0.f;
        const float p5 = (5 < nv) ? __expf(s5v - m) : 0.f;
        const float p6 = (6 < nv) ? __expf(s6v - m) : 0.f;
        const float p7 = (7 < nv) ? __expf(s7v - m) : 0.f;

        s += ((p0 + p1) + (p2 + p3)) + ((p4 + p5) + (p6 + p7));

        a0 += p0 * xa0.x + p1 * xa1.x + p2 * xa2.x + p3 * xa3.x +
              p4 * xa4.x + p5 * xa5.x + p6 * xa6.x + p7 * xa7.x;
        a1 += p0 * xa0.y + p1 * xa1.y + p2 * xa2.y + p3 * xa3.y +
              p4 * xa4.y + p5 * xa5.y + p6 * xa6.y + p7 * xa7.y;
        a2 += p0 * xa0.z + p1 * xa1.z + p2 * xa2.z + p3 * xa3.z +
              p4 * xa4.z + p5 * xa5.z + p6 * xa6.z + p7 * xa7.z;
        a3 += p0 * xa0.w + p1 * xa1.w + p2 * xa2.w + p3 * xa3.w +
              p4 * xa4.w + p5 * xa5.w + p6 * xa6.w + p7 * xa7.w;
        a4 += p0 * xb0.x + p1 * xb1.x + p2 * xb2.x + p3 * xb3.x +
              p4 * xb4.x + p5 * xb5.x + p6 * xb6.x + p7 * xb7.x;
        a5 += p0 * xb0.y + p1 * xb1.y + p2 * xb2.y + p3 * xb3.y +
              p4 * xb4.y + p5 * xb5.y + p6 * xb6.y + p7 * xb7.y;
    }

    // Accumulator layout: a0..a3 = elems 4*lane+{0..3}; a4,a5 = 256+2*lane+{0,1}
    *(float4*)&la[wave][4 * lane] = make_float4(a0, a1, a2, a3);
    *(float2*)&la[wave][256 + 2 * lane] = make_float2(a4, a5);
    if (lane == 0) { lm[wave] = m; lss[wave] = s; }
    __syncthreads();

    const float M = fmaxf(fmaxf(lm[0], lm[1]), fmaxf(lm[2], lm[3]));
    const float w0 = (lm[0] == -INFINITY) ? 0.f : __expf(lm[0] - M);
    const float w1 = (lm[1] == -INFINITY) ? 0.f : __expf(lm[1] - M);
    const float w2 = (lm[2] == -INFINITY) ? 0.f : __expf(lm[2] - M);
    const float w3 = (lm[3] == -INFINITY) ? 0.f : __expf(lm[3] - M);
    const float S = w0 * lss[0] + w1 * lss[1] + w2 * lss[2] + w3 * lss[3];
    if (t == 0) { pm[blk] = M; ps[blk] = S; }
    for (int idx = t; idx < DD; idx += 256) {
        pa[(size_t)blk * DD + idx] =
            w0 * la[0][idx] + w1 * la[1][idx] + w2 * la[2][idx] + w3 * la[3][idx];
    }

    // ---- publish partial, last block of batch does the finish ----
    __threadfence();                 // each thread publishes its pa/pm/ps writes
    __syncthreads();                 // all threads of block have fenced

    __shared__ int s_last;
    if (t == 0) s_last = (atomicAdd(&counters[b], 1) == CHUNKS - 1) ? 1 : 0;
    __syncthreads();
    if (!s_last) return;
    __threadfence();                 // acquire: see other blocks' published writes

    // ---- finish for batch b (one block) ----
    __shared__ float wg[CHUNKS];
    __shared__ float an[DD];
    __shared__ float z[LL + DD];
    __shared__ float hid[LL];

    float Mg = -INFINITY;
#pragma unroll
    for (int i = 0; i < CHUNKS; ++i) Mg = fmaxf(Mg, pm[b * CHUNKS + i]);
    if (t < CHUNKS) {
        const float mi2 = pm[b * CHUNKS + t];
        wg[t] = (mi2 == -INFINITY) ? 0.f : __expf(mi2 - Mg);
    }
    __syncthreads();

    float Sg = 0.f;
#pragma unroll
    for (int i = 0; i < CHUNKS; ++i) Sg += wg[i] * ps[b * CHUNKS + i];
    const float invS = 1.f / Sg;

    for (int d = t; d < DD; d += 256) {   // coalesced across d
        float av = 0.f;
#pragma unroll
        for (int i = 0; i < CHUNKS; ++i)
            av += wg[i] * pa[(size_t)(b * CHUNKS + i) * DD + d];
        an[d] = av * invS;
    }
    __syncthreads();

    if (t < LL) {
        float acc = bv[t];
#pragma unroll 4
        for (int d = 0; d < DD; ++d) acc += an[d] * Wv[d * LL + t];
        z[t] = acc;
    }
    for (int j = t; j < DD; j += 256) z[LL + j] = target[b * DD + j];
    __syncthreads();

    if (t < LL) {
        float hacc = b1[t];
#pragma unroll 4
        for (int j = 0; j < LL + DD; ++j) hacc += z[j] * W1[j * LL + t];
        hid[t] = fmaxf(hacc, 0.f);
    }
    __syncthreads();

    if (t < LL) {
        float oacc = b2[t];
#pragma unroll 4
        for (int j = 0; j < LL; ++j) oacc += hid[j] * W2[j * LL + t];
        out[b * LL + t] = oacc;
    }
}

// ---------------------------------------------------------------------------
extern "C" void kernel_launch(void* const* d_in, const int* in_sizes, int n_in,
                              void* d_out, int out_size, void* d_ws, size_t ws_size,
                              hipStream_t stream)
{
    const float* target = (const float*)d_in[0];
    const float* h      = (const float*)d_in[1];
    const void*  mask   = d_in[2];
    const float* Wq = (const float*)d_in[3];
    const float* bq = (const float*)d_in[4];
    const float* Wk = (const float*)d_in[5];
    const float* bk = (const float*)d_in[6];
    const float* Wv = (const float*)d_in[7];
    const float* bv = (const float*)d_in[8];
    const float* W1 = (const float*)d_in[9];
    const float* b1 = (const float*)d_in[10];
    const float* W2 = (const float*)d_in[11];
    const float* b2 = (const float*)d_in[12];
    float* out = (float*)d_out;

    float* ws = (float*)d_ws;
    int*   flag = (int*)d_ws;
    float* u  = ws + 64;                  // 32*384
    float* c  = u + NB * DD;              // 32
    float* pm = c + NB;                   // 1024
    float* ps = pm + NB * CHUNKS;         // 1024
    float* pa = ps + NB * CHUNKS;         // 1024*384
    int* counters = (int*)(pa + (size_t)NB * CHUNKS * DD);  // 32 ints

    hipLaunchKernelGGL(ga_prep, dim3(NB), dim3(DD), 0, stream,
                       target, Wq, bq, Wk, bk, mask, u, c, flag, counters);
    hipLaunchKernelGGL(ga_stream, dim3(NB * CHUNKS), dim3(256), 0, stream,
                       h, mask, u, c, flag, pm, ps, pa, counters,
                       target, Wv, bv, W1, b1, W2, b2, out);
}

// Round 6
// 105.416 us; speedup vs baseline: 2.5697x; 2.5697x over previous
//
#include <hip/hip_runtime.h>
#include <math.h>

// Problem constants (from reference)
#define NB 32      // batch
#define NN 8192    // neighbors
#define DD 384     // feature dim
#define LL 128     // latent dim
#define CHUNKS 32  // blocks per batch in stream kernel
#define RPB 256    // rows per block (NN/CHUNKS)
#define NWAVES 4   // waves per block
#define RPW 64     // rows per wave

// ---------------------------------------------------------------------------
// Kernel A: per-batch q = target@Wq+bq (internal), then u = scale*(Wk@q),
// c = scale*(bk.q). All loads coalesced (Wk via per-row float2 + butterfly).
// Block 0 probes the mask dtype encoding.
// ---------------------------------------------------------------------------
__global__ __launch_bounds__(384) void ga_prep(
    const float* __restrict__ target,
    const float* __restrict__ Wq, const float* __restrict__ bq,
    const float* __restrict__ Wk, const float* __restrict__ bk,
    const void* __restrict__ mask,
    float* __restrict__ u, float* __restrict__ c, int* __restrict__ flag)
{
    const int b = blockIdx.x;   // 32 blocks
    const int t = threadIdx.x;  // 384 threads
    const int w = t >> 6;       // wave 0..5
    const int l = t & 63;       // lane

    __shared__ float tgt[DD];
    __shared__ __align__(16) float qs[LL];
    __shared__ float qp[3][LL];
    __shared__ int s_notint, s_notflt;

    if (b == 0 && t == 0) { s_notint = 0; s_notflt = 0; }
    tgt[t] = target[b * DD + t];
    __syncthreads();

    // Mask dtype probe (block 0 only): int32 {0,1} vs float32 vs bytes
    if (b == 0 && t < 256) {
        unsigned v = ((const unsigned*)mask)[t];
        if (v > 1u) s_notint = 1;                       // benign race, all write 1
        if (v != 0u && v != 0x3F800000u) s_notflt = 1;
    }

    // q[ll] = bq[ll] + sum_d tgt[d]*Wq[d*128+ll], split d into 3 segments
    const int ll = t & (LL - 1);
    const int seg = t >> 7;  // 0..2
    float acc = 0.f;
#pragma unroll 4
    for (int i = 0; i < 128; ++i) {
        int d = seg * 128 + i;
        acc += tgt[d] * Wq[d * LL + ll];  // coalesced across ll
    }
    qp[seg][ll] = acc;
    __syncthreads();
    if (t < LL) qs[t] = qp[0][t] + qp[1][t] + qp[2][t] + bq[t];
    __syncthreads();

    const float scale = 0.051031036307982884f;  // 1/sqrt(384)

    // c[b] = scale * dot(bk, qs): wave 0, lane-parallel float2 + butterfly
    if (w == 0) {
        const float2 bk2 = *(const float2*)&bk[2 * l];
        const float2 q2  = *(const float2*)&qs[2 * l];
        float part = bk2.x * q2.x + bk2.y * q2.y;
#pragma unroll
        for (int off = 32; off; off >>= 1) part += __shfl_xor(part, off, 64);
        if (l == 0) c[b] = part * scale;
    }

    // u[d] = scale * sum_l Wk[d*128+l]*qs[l]; wave w handles rows w*64..w*64+63
    const float2 q2 = *(const float2*)&qs[2 * l];
    for (int r = 0; r < 64; ++r) {
        const int d = w * 64 + r;
        const float2 wk = *(const float2*)&Wk[d * LL + 2 * l];
        float part = wk.x * q2.x + wk.y * q2.y;
#pragma unroll
        for (int off = 32; off; off >>= 1) part += __shfl_xor(part, off, 64);
        if (l == 0) u[b * DD + d] = part * scale;
    }

    __syncthreads();
    if (b == 0 && t == 0) *flag = s_notint ? (s_notflt ? 2 : 1) : 0;
}

// ---------------------------------------------------------------------------
// Kernel B: stream h (mask-skip) with REGISTER PING-PONG PREFETCH: 4-row
// stages; stage k+1's 8 load instrs issue before stage k's compute, so
// load latency hides under the shfl/exp dependency chain. Online softmax,
// 384-wide accumulator (6 f32/lane). Block merge in LDS.
// ---------------------------------------------------------------------------

#define GA_LOAD4(Xa, Xb, B2) do {                                        \
    _Pragma("unroll")                                                    \
    for (int j = 0; j < 4; ++j) {                                        \
        const int rr = ((B2) + j < cnt) ? wlist[wave][(B2) + j] : 0;     \
        const float* rp = hb + (size_t)rr * DD;                          \
        Xa[j] = *(const float4*)(rp + 4 * lane);                         \
        Xb[j] = *(const float2*)(rp + 256 + 2 * lane);                   \
    } } while (0)

#define GA_COMP4(Xa, Xb, B2) do {                                        \
    float dd[4];                                                         \
    _Pragma("unroll")                                                    \
    for (int j = 0; j < 4; ++j)                                          \
        dd[j] = Xa[j].x * ua.x + Xa[j].y * ua.y + Xa[j].z * ua.z +       \
                Xa[j].w * ua.w + Xb[j].x * ub2.x + Xb[j].y * ub2.y;      \
    _Pragma("unroll")                                                    \
    for (int off = 32; off; off >>= 1) {                                 \
        _Pragma("unroll")                                                \
        for (int j = 0; j < 4; ++j) dd[j] += __shfl_xor(dd[j], off, 64); \
    }                                                                    \
    const int nv = cnt - (B2);                                           \
    float sv[4];                                                         \
    _Pragma("unroll")                                                    \
    for (int j = 0; j < 4; ++j)                                          \
        sv[j] = (j < nv) ? dd[j] + cc : -INFINITY;                       \
    float M4 = fmaxf(fmaxf(sv[0], sv[1]), fmaxf(sv[2], sv[3]));          \
    const float mn = fmaxf(m, M4);                                       \
    const float f = __expf(m - mn);  /* first stage: exp(-inf)=0 */      \
    m = mn;                                                              \
    s *= f;                                                              \
    a0 *= f; a1 *= f; a2 *= f; a3 *= f; a4 *= f; a5 *= f;                \
    float pp[4];                                                         \
    _Pragma("unroll")                                                    \
    for (int j = 0; j < 4; ++j)                                          \
        pp[j] = (j < nv) ? __expf(sv[j] - m) : 0.f;                      \
    s += (pp[0] + pp[1]) + (pp[2] + pp[3]);                              \
    _Pragma("unroll")                                                    \
    for (int j = 0; j < 4; ++j) {                                        \
        a0 += pp[j] * Xa[j].x; a1 += pp[j] * Xa[j].y;                    \
        a2 += pp[j] * Xa[j].z; a3 += pp[j] * Xa[j].w;                    \
        a4 += pp[j] * Xb[j].x; a5 += pp[j] * Xb[j].y;                    \
    } } while (0)

__global__ __launch_bounds__(256, 4) void ga_stream(
    const float* __restrict__ h, const void* __restrict__ mask,
    const float* __restrict__ u, const float* __restrict__ c,
    const int* __restrict__ flag,
    float* __restrict__ pm, float* __restrict__ ps, float* __restrict__ pa)
{
    const int blk = blockIdx.x;           // 1024 blocks
    const int b = blk >> 5;               // batch
    const int chunk = blk & (CHUNKS - 1);
    const int wave = threadIdx.x >> 6;
    const int lane = threadIdx.x & 63;
    const int t = threadIdx.x;

    // u fragment: float4 over elems [0,256), float2 over [256,384)
    const float* ubase = u + b * DD;
    const float4 ua  = *(const float4*)(ubase + 4 * lane);
    const float2 ub2 = *(const float2*)(ubase + 256 + 2 * lane);
    const float cc = c[b];

    const int n0 = chunk * RPB + wave * RPW;
    const size_t rowbase = (size_t)b * NN + n0;
    const float* hb = h + rowbase * DD;

    // Gather this wave's 64 mask bits -> ballot, compact indices into LDS
    const int fm = *flag;
    int myMask;
    const size_t mi = rowbase + lane;
    if (fm == 0)      myMask = ((const int*)mask)[mi] != 0;
    else if (fm == 1) myMask = ((const unsigned*)mask)[mi] != 0u;
    else              myMask = ((const unsigned char*)mask)[mi] != 0;
    const unsigned long long mbits = __ballot(myMask);
    const int cnt = __popcll(mbits);
    const int pos = __popcll(mbits & ((1ull << lane) - 1ull));

    __shared__ int wlist[NWAVES][64];
    __shared__ float lm[NWAVES], lss[NWAVES];
    __shared__ float la[NWAVES][DD];

    if (myMask) wlist[wave][pos] = lane;   // wave-synchronous, no barrier needed

    float m = -INFINITY, s = 0.f;
    float a0 = 0.f, a1 = 0.f, a2 = 0.f, a3 = 0.f, a4 = 0.f, a5 = 0.f;

    float4 Axa[4]; float2 Axb[4];
    float4 Bxa[4]; float2 Bxb[4];

    if (cnt > 0) {
        GA_LOAD4(Axa, Axb, 0);
        int base = 0;
        while (true) {
            if (base + 4 < cnt) GA_LOAD4(Bxa, Bxb, base + 4);   // prefetch
            GA_COMP4(Axa, Axb, base);
            base += 4;
            if (base >= cnt) break;
            if (base + 4 < cnt) GA_LOAD4(Axa, Axb, base + 4);   // prefetch
            GA_COMP4(Bxa, Bxb, base);
            base += 4;
            if (base >= cnt) break;
        }
    }

    // Accumulator layout: a0..a3 = elems 4*lane+{0..3}; a4,a5 = 256+2*lane+{0,1}
    *(float4*)&la[wave][4 * lane] = make_float4(a0, a1, a2, a3);
    *(float2*)&la[wave][256 + 2 * lane] = make_float2(a4, a5);
    if (lane == 0) { lm[wave] = m; lss[wave] = s; }
    __syncthreads();

    const float M = fmaxf(fmaxf(lm[0], lm[1]), fmaxf(lm[2], lm[3]));
    const float w0 = (lm[0] == -INFINITY) ? 0.f : __expf(lm[0] - M);
    const float w1 = (lm[1] == -INFINITY) ? 0.f : __expf(lm[1] - M);
    const float w2 = (lm[2] == -INFINITY) ? 0.f : __expf(lm[2] - M);
    const float w3 = (lm[3] == -INFINITY) ? 0.f : __expf(lm[3] - M);
    const float S = w0 * lss[0] + w1 * lss[1] + w2 * lss[2] + w3 * lss[3];
    if (t == 0) { pm[blk] = M; ps[blk] = S; }
    for (int idx = t; idx < DD; idx += 256) {
        pa[(size_t)blk * DD + idx] =
            w0 * la[0][idx] + w1 * la[1][idx] + w2 * la[2][idx] + w3 * la[3][idx];
    }
}

// ---------------------------------------------------------------------------
// Kernel C: per batch, reduce 32 partials -> a_norm[384]; nws = a_norm@Wv+bv;
// z=[nws,target]; out = relu(z@W1+b1)@W2+b2. 384 threads, all matvecs via
// 3-segment coalesced partial sums (no long serial dot loops).
// ---------------------------------------------------------------------------
__global__ __launch_bounds__(384) void ga_finish(
    const float* __restrict__ target,
    const float* __restrict__ Wv, const float* __restrict__ bv,
    const float* __restrict__ W1, const float* __restrict__ b1,
    const float* __restrict__ W2, const float* __restrict__ b2,
    const float* __restrict__ pm, const float* __restrict__ ps,
    const float* __restrict__ pa, float* __restrict__ out)
{
    const int b = blockIdx.x;   // 32 blocks
    const int t = threadIdx.x;  // 384 threads
    const int l = t & (LL - 1);
    const int seg = t >> 7;     // 0..2

    __shared__ float wg[CHUNKS];
    __shared__ float an[DD];
    __shared__ float z[LL + DD];   // 512
    __shared__ float hp[3][LL];
    __shared__ float hid[LL];

    // Global max / weights across the 32 chunk partials
    float M = -INFINITY;
#pragma unroll
    for (int i = 0; i < CHUNKS; ++i) M = fmaxf(M, pm[b * CHUNKS + i]);
    if (t < CHUNKS) {
        const float mi = pm[b * CHUNKS + t];
        wg[t] = (mi == -INFINITY) ? 0.f : __expf(mi - M);
    }
    __syncthreads();

    float S = 0.f;
#pragma unroll
    for (int i = 0; i < CHUNKS; ++i) S += wg[i] * ps[b * CHUNKS + i];
    const float invS = 1.f / S;

    // an[t]: thread t owns feature t (coalesced pa reads per chunk)
    float av = 0.f;
#pragma unroll
    for (int i = 0; i < CHUNKS; ++i)
        av += wg[i] * pa[(size_t)(b * CHUNKS + i) * DD + t];
    an[t] = av * invS;
    z[LL + t] = target[b * DD + t];
    __syncthreads();

    // nws[l] = bv[l] + sum_d an[d]*Wv[d*128+l]  (3 segments of 128)
    {
        float acc = 0.f;
#pragma unroll 4
        for (int i = 0; i < 128; ++i) {
            const int d = seg * 128 + i;
            acc += an[d] * Wv[d * LL + l];   // coalesced across l
        }
        hp[seg][l] = acc;
    }
    __syncthreads();
    if (t < LL) z[t] = hp[0][t] + hp[1][t] + hp[2][t] + bv[t];
    __syncthreads();

    // hid[l] = relu(b1[l] + sum_j z[j]*W1[j*128+l]), j in [0,512): segs 171/171/170
    {
        const int start = seg * 171;
        const int len = (seg < 2) ? 171 : 170;
        float acc = 0.f;
#pragma unroll 4
        for (int k = 0; k < len; ++k) {
            const int j = start + k;
            acc += z[j] * W1[j * LL + l];
        }
        hp[seg][l] = acc;
    }
    __syncthreads();
    if (t < LL) hid[t] = fmaxf(hp[0][t] + hp[1][t] + hp[2][t] + b1[t], 0.f);
    __syncthreads();

    // out[l] = b2[l] + sum_j hid[j]*W2[j*128+l], j in [0,128): segs 43/43/42
    {
        const int start = seg * 43;
        const int len = (seg < 2) ? 43 : 42;
        float acc = 0.f;
#pragma unroll 4
        for (int k = 0; k < len; ++k) {
            const int j = start + k;
            acc += hid[j] * W2[j * LL + l];
        }
        hp[seg][l] = acc;
    }
    __syncthreads();
    if (t < LL) out[b * LL + t] = hp[0][t] + hp[1][t] + hp[2][t] + b2[t];
}

// ---------------------------------------------------------------------------
extern "C" void kernel_launch(void* const* d_in, const int* in_sizes, int n_in,
                              void* d_out, int out_size, void* d_ws, size_t ws_size,
                              hipStream_t stream)
{
    const float* target = (const float*)d_in[0];
    const float* h      = (const float*)d_in[1];
    const void*  mask   = d_in[2];
    const float* Wq = (const float*)d_in[3];
    const float* bq = (const float*)d_in[4];
    const float* Wk = (const float*)d_in[5];
    const float* bk = (const float*)d_in[6];
    const float* Wv = (const float*)d_in[7];
    const float* bv = (const float*)d_in[8];
    const float* W1 = (const float*)d_in[9];
    const float* b1 = (const float*)d_in[10];
    const float* W2 = (const float*)d_in[11];
    const float* b2 = (const float*)d_in[12];
    float* out = (float*)d_out;

    float* ws = (float*)d_ws;
    int*   flag = (int*)d_ws;
    float* u  = ws + 64;                  // 32*384
    float* c  = u + NB * DD;              // 32
    float* pm = c + NB;                   // 1024
    float* ps = pm + NB * CHUNKS;         // 1024
    float* pa = ps + NB * CHUNKS;         // 1024*384

    hipLaunchKernelGGL(ga_prep, dim3(NB), dim3(DD), 0, stream,
                       target, Wq, bq, Wk, bk, mask, u, c, flag);
    hipLaunchKernelGGL(ga_stream, dim3(NB * CHUNKS), dim3(256), 0, stream,
                       h, mask, u, c, flag, pm, ps, pa);
    hipLaunchKernelGGL(ga_finish, dim3(NB), dim3(384), 0, stream,
                       target, Wv, bv, W1, b1, W2, b2, pm, ps, pa, out);
}

// Round 7
// 68.896 us; speedup vs baseline: 3.9317x; 1.5301x over previous
//
#include <hip/hip_runtime.h>
#include <math.h>

// Problem constants (from reference)
#define NB 32      // batch
#define NN 8192    // neighbors
#define DD 384     // feature dim
#define LL 128     // latent dim
#define CHUNKS 32  // blocks per batch in stream kernel
#define RPB 256    // rows per block (NN/CHUNKS)
#define NWAVES 4   // waves per block
#define RPW 64     // rows per wave

// ---------------------------------------------------------------------------
// Kernel A: per-batch q = target@Wq+bq (internal), then u = scale*(Wk@q),
// c = scale*(bk.q). Wk is L2-warmed during the q matvec; u uses a dual-row
// half-wave butterfly (2 rows/iter, 5 shfl levels, 2 independent chains).
// Block 0 probes the mask dtype encoding.
// ---------------------------------------------------------------------------
__global__ __launch_bounds__(384) void ga_prep(
    const float* __restrict__ target,
    const float* __restrict__ Wq, const float* __restrict__ bq,
    const float* __restrict__ Wk, const float* __restrict__ bk,
    const void* __restrict__ mask,
    float* __restrict__ u, float* __restrict__ c, int* __restrict__ flag)
{
    const int b = blockIdx.x;   // 32 blocks
    const int t = threadIdx.x;  // 384 threads
    const int w = t >> 6;       // wave 0..5
    const int l = t & 63;       // lane

    __shared__ float tgt[DD];
    __shared__ __align__(16) float qs[LL];
    __shared__ float qp[3][LL];
    __shared__ int s_notint, s_notflt;

    if (b == 0 && t == 0) { s_notint = 0; s_notflt = 0; }
    tgt[t] = target[b * DD + t];

    // Warm Wk into this XCD's L2 while q is being computed: 8 stride-64B
    // touches per thread cover all 3072 cache lines of Wk (196 KB).
    {
        float wsum = 0.f;
#pragma unroll
        for (int k = 0; k < 8; ++k) wsum += Wk[t * 16 + k * 6144];
        asm volatile("" :: "v"(wsum));
    }
    __syncthreads();

    // Mask dtype probe (block 0 only): int32 {0,1} vs float32 vs bytes
    if (b == 0 && t < 256) {
        unsigned v = ((const unsigned*)mask)[t];
        if (v > 1u) s_notint = 1;                       // benign race, all write 1
        if (v != 0u && v != 0x3F800000u) s_notflt = 1;
    }

    // q[ll] = bq[ll] + sum_d tgt[d]*Wq[d*128+ll], split d into 3 segments
    const int ll = t & (LL - 1);
    const int seg = t >> 7;  // 0..2
    float acc = 0.f;
#pragma unroll 4
    for (int i = 0; i < 128; ++i) {
        int d = seg * 128 + i;
        acc += tgt[d] * Wq[d * LL + ll];  // coalesced across ll
    }
    qp[seg][ll] = acc;
    __syncthreads();
    if (t < LL) qs[t] = qp[0][t] + qp[1][t] + qp[2][t] + bq[t];
    __syncthreads();

    const float scale = 0.051031036307982884f;  // 1/sqrt(384)

    // c[b] = scale * dot(bk, qs): wave 0, lane-parallel float2 + butterfly
    if (w == 0) {
        const float2 bk2 = *(const float2*)&bk[2 * l];
        const float2 q2  = *(const float2*)&qs[2 * l];
        float part = bk2.x * q2.x + bk2.y * q2.y;
#pragma unroll
        for (int off = 32; off; off >>= 1) part += __shfl_xor(part, off, 64);
        if (l == 0) c[b] = part * scale;
    }

    // u[d] = scale * (Wk[d,:] . qs). Wave w owns rows [w*64, w*64+64).
    // Half-wave scheme: lanes 0..31 do row d, lanes 32..63 row d+1 (float4,
    // contiguous 1KB per instr); 5-level xor reduce stays within each half.
    // Two dual-row ops per iteration -> 2 independent shfl chains.
    {
        const int hw = l >> 5;      // 0 or 1
        const int j  = l & 31;      // 0..31
        const float4 q4 = *(const float4*)&qs[4 * j];
        for (int k = 0; k < 64; k += 4) {
            const int rowk = w * 64 + k;
            const int dA = rowk + hw;
            const int dB = rowk + 2 + hw;
            const float4 wkA = *(const float4*)&Wk[dA * LL + 4 * j];
            const float4 wkB = *(const float4*)&Wk[dB * LL + 4 * j];
            float pA = wkA.x * q4.x + wkA.y * q4.y + wkA.z * q4.z + wkA.w * q4.w;
            float pB = wkB.x * q4.x + wkB.y * q4.y + wkB.z * q4.z + wkB.w * q4.w;
#pragma unroll
            for (int off = 16; off; off >>= 1) {
                pA += __shfl_xor(pA, off, 64);
                pB += __shfl_xor(pB, off, 64);
            }
            if (j == 0) {   // lanes 0 and 32
                u[b * DD + dA] = pA * scale;
                u[b * DD + dB] = pB * scale;
            }
        }
    }

    __syncthreads();
    if (b == 0 && t == 0) *flag = s_notint ? (s_notflt ? 2 : 1) : 0;
}

// ---------------------------------------------------------------------------
// Kernel B: stream h (mask-skip) with register ping-pong prefetch (4-row
// stages). At block end, warm a 4KB slice of {Wv,W1,W2} into this XCD's L2
// for ga_finish. Online softmax, 384-wide accumulator. Block merge in LDS.
// ---------------------------------------------------------------------------

#define GA_LOAD4(Xa, Xb, B2) do {                                        \
    _Pragma("unroll")                                                    \
    for (int j = 0; j < 4; ++j) {                                        \
        const int rr = ((B2) + j < cnt) ? wlist[wave][(B2) + j] : 0;     \
        const float* rp = hb + (size_t)rr * DD;                          \
        Xa[j] = *(const float4*)(rp + 4 * lane);                         \
        Xb[j] = *(const float2*)(rp + 256 + 2 * lane);                   \
    } } while (0)

#define GA_COMP4(Xa, Xb, B2) do {                                        \
    float dd[4];                                                         \
    _Pragma("unroll")                                                    \
    for (int j = 0; j < 4; ++j)                                          \
        dd[j] = Xa[j].x * ua.x + Xa[j].y * ua.y + Xa[j].z * ua.z +       \
                Xa[j].w * ua.w + Xb[j].x * ub2.x + Xb[j].y * ub2.y;      \
    _Pragma("unroll")                                                    \
    for (int off = 32; off; off >>= 1) {                                 \
        _Pragma("unroll")                                                \
        for (int j = 0; j < 4; ++j) dd[j] += __shfl_xor(dd[j], off, 64); \
    }                                                                    \
    const int nv = cnt - (B2);                                           \
    float sv[4];                                                         \
    _Pragma("unroll")                                                    \
    for (int j = 0; j < 4; ++j)                                          \
        sv[j] = (j < nv) ? dd[j] + cc : -INFINITY;                       \
    float M4 = fmaxf(fmaxf(sv[0], sv[1]), fmaxf(sv[2], sv[3]));          \
    const float mn = fmaxf(m, M4);                                       \
    const float f = __expf(m - mn);  /* first stage: exp(-inf)=0 */      \
    m = mn;                                                              \
    s *= f;                                                              \
    a0 *= f; a1 *= f; a2 *= f; a3 *= f; a4 *= f; a5 *= f;                \
    float pp[4];                                                         \
    _Pragma("unroll")                                                    \
    for (int j = 0; j < 4; ++j)                                          \
        pp[j] = (j < nv) ? __expf(sv[j] - m) : 0.f;                      \
    s += (pp[0] + pp[1]) + (pp[2] + pp[3]);                              \
    _Pragma("unroll")                                                    \
    for (int j = 0; j < 4; ++j) {                                        \
        a0 += pp[j] * Xa[j].x; a1 += pp[j] * Xa[j].y;                    \
        a2 += pp[j] * Xa[j].z; a3 += pp[j] * Xa[j].w;                    \
        a4 += pp[j] * Xb[j].x; a5 += pp[j] * Xb[j].y;                    \
    } } while (0)

__global__ __launch_bounds__(256, 4) void ga_stream(
    const float* __restrict__ h, const void* __restrict__ mask,
    const float* __restrict__ u, const float* __restrict__ c,
    const int* __restrict__ flag,
    float* __restrict__ pm, float* __restrict__ ps, float* __restrict__ pa,
    const float* __restrict__ Wv, const float* __restrict__ W1,
    const float* __restrict__ W2)
{
    const int blk = blockIdx.x;           // 1024 blocks
    const int b = blk >> 5;               // batch
    const int chunk = blk & (CHUNKS - 1);
    const int wave = threadIdx.x >> 6;
    const int lane = threadIdx.x & 63;
    const int t = threadIdx.x;

    // u fragment: float4 over elems [0,256), float2 over [256,384)
    const float* ubase = u + b * DD;
    const float4 ua  = *(const float4*)(ubase + 4 * lane);
    const float2 ub2 = *(const float2*)(ubase + 256 + 2 * lane);
    const float cc = c[b];

    const int n0 = chunk * RPB + wave * RPW;
    const size_t rowbase = (size_t)b * NN + n0;
    const float* hb = h + rowbase * DD;

    // Gather this wave's 64 mask bits -> ballot, compact indices into LDS
    const int fm = *flag;
    int myMask;
    const size_t mi = rowbase + lane;
    if (fm == 0)      myMask = ((const int*)mask)[mi] != 0;
    else if (fm == 1) myMask = ((const unsigned*)mask)[mi] != 0u;
    else              myMask = ((const unsigned char*)mask)[mi] != 0;
    const unsigned long long mbits = __ballot(myMask);
    const int cnt = __popcll(mbits);
    const int pos = __popcll(mbits & ((1ull << lane) - 1ull));

    __shared__ int wlist[NWAVES][64];
    __shared__ float lm[NWAVES], lss[NWAVES];
    __shared__ float la[NWAVES][DD];

    if (myMask) wlist[wave][pos] = lane;   // wave-synchronous, no barrier needed

    float m = -INFINITY, s = 0.f;
    float a0 = 0.f, a1 = 0.f, a2 = 0.f, a3 = 0.f, a4 = 0.f, a5 = 0.f;

    float4 Axa[4]; float2 Axb[4];
    float4 Bxa[4]; float2 Bxb[4];

    if (cnt > 0) {
        GA_LOAD4(Axa, Axb, 0);
        int base = 0;
        while (true) {
            if (base + 4 < cnt) GA_LOAD4(Bxa, Bxb, base + 4);   // prefetch
            GA_COMP4(Axa, Axb, base);
            base += 4;
            if (base >= cnt) break;
            if (base + 4 < cnt) GA_LOAD4(Axa, Axb, base + 4);   // prefetch
            GA_COMP4(Bxa, Bxb, base);
            base += 4;
            if (base >= cnt) break;
        }
    }

    // ---- L2-warm a 4KB slice of {Wv|W1|W2} (512KB total over 128 slices;
    // slice id cycles with blk>>3 so every XCD sees all slices). Pinned
    // after the main loop so the lines survive until ga_finish.
    __builtin_amdgcn_sched_barrier(0);
    {
        const int slice = (blk >> 3) & 127;
        const int idx = slice * 1024 + t * 4;   // float index into 128K-float concat
        const float* p = (idx < 49152) ? (Wv + idx)
                       : (idx < 114688) ? (W1 + (idx - 49152))
                                        : (W2 + (idx - 114688));
        const float4 wv4 = *(const float4*)p;
        asm volatile("" :: "v"(wv4.x), "v"(wv4.y), "v"(wv4.z), "v"(wv4.w));
    }

    // Accumulator layout: a0..a3 = elems 4*lane+{0..3}; a4,a5 = 256+2*lane+{0,1}
    *(float4*)&la[wave][4 * lane] = make_float4(a0, a1, a2, a3);
    *(float2*)&la[wave][256 + 2 * lane] = make_float2(a4, a5);
    if (lane == 0) { lm[wave] = m; lss[wave] = s; }
    __syncthreads();

    const float M = fmaxf(fmaxf(lm[0], lm[1]), fmaxf(lm[2], lm[3]));
    const float w0 = (lm[0] == -INFINITY) ? 0.f : __expf(lm[0] - M);
    const float w1 = (lm[1] == -INFINITY) ? 0.f : __expf(lm[1] - M);
    const float w2 = (lm[2] == -INFINITY) ? 0.f : __expf(lm[2] - M);
    const float w3 = (lm[3] == -INFINITY) ? 0.f : __expf(lm[3] - M);
    const float S = w0 * lss[0] + w1 * lss[1] + w2 * lss[2] + w3 * lss[3];
    if (t == 0) { pm[blk] = M; ps[blk] = S; }
    for (int idx = t; idx < DD; idx += 256) {
        pa[(size_t)blk * DD + idx] =
            w0 * la[0][idx] + w1 * la[1][idx] + w2 * la[2][idx] + w3 * la[3][idx];
    }
}

// ---------------------------------------------------------------------------
// Kernel C: per batch, reduce 32 partials -> a_norm[384]; nws = a_norm@Wv+bv;
// z=[nws,target]; out = relu(z@W1+b1)@W2+b2. 512 threads; every matvec is
// 4-way j-segmented with 4 independent accumulators (deep load pipelining).
// ---------------------------------------------------------------------------
__global__ __launch_bounds__(512) void ga_finish(
    const float* __restrict__ target,
    const float* __restrict__ Wv, const float* __restrict__ bv,
    const float* __restrict__ W1, const float* __restrict__ b1,
    const float* __restrict__ W2, const float* __restrict__ b2,
    const float* __restrict__ pm, const float* __restrict__ ps,
    const float* __restrict__ pa, float* __restrict__ out)
{
    const int b = blockIdx.x;   // 32 blocks
    const int t = threadIdx.x;  // 512 threads
    const int l = t & (LL - 1);
    const int seg = t >> 7;     // 0..3

    __shared__ float wg[CHUNKS];
    __shared__ float an[DD];
    __shared__ float z[LL + DD];   // 512
    __shared__ float hp[4][LL];
    __shared__ float hid[LL];

    // Global max / weights across the 32 chunk partials
    float M = -INFINITY;
#pragma unroll
    for (int i = 0; i < CHUNKS; ++i) M = fmaxf(M, pm[b * CHUNKS + i]);
    if (t < CHUNKS) {
        const float mi = pm[b * CHUNKS + t];
        wg[t] = (mi == -INFINITY) ? 0.f : __expf(mi - M);
    }
    __syncthreads();

    float S = 0.f;
#pragma unroll
    for (int i = 0; i < CHUNKS; ++i) S += wg[i] * ps[b * CHUNKS + i];
    const float invS = 1.f / S;

    // an[t]: thread t owns feature t (coalesced pa reads; 4 indep accs)
    if (t < DD) {
        float v0 = 0.f, v1 = 0.f, v2 = 0.f, v3 = 0.f;
#pragma unroll
        for (int i = 0; i < CHUNKS; i += 4) {
            v0 += wg[i]     * pa[(size_t)(b * CHUNKS + i)     * DD + t];
            v1 += wg[i + 1] * pa[(size_t)(b * CHUNKS + i + 1) * DD + t];
            v2 += wg[i + 2] * pa[(size_t)(b * CHUNKS + i + 2) * DD + t];
            v3 += wg[i + 3] * pa[(size_t)(b * CHUNKS + i + 3) * DD + t];
        }
        an[t] = ((v0 + v1) + (v2 + v3)) * invS;
        z[LL + t] = target[b * DD + t];
    }
    __syncthreads();

    // nws[l] = bv[l] + sum_d an[d]*Wv[d*128+l]; 4 segments x 96 d's
    {
        const int start = seg * 96;
        float v0 = 0.f, v1 = 0.f, v2 = 0.f, v3 = 0.f;
#pragma unroll 2
        for (int k = 0; k < 96; k += 4) {
            const int d = start + k;
            v0 += an[d]     * Wv[(d)     * LL + l];
            v1 += an[d + 1] * Wv[(d + 1) * LL + l];
            v2 += an[d + 2] * Wv[(d + 2) * LL + l];
            v3 += an[d + 3] * Wv[(d + 3) * LL + l];
        }
        hp[seg][l] = (v0 + v1) + (v2 + v3);
    }
    __syncthreads();
    if (t < LL) z[t] = (hp[0][t] + hp[1][t]) + (hp[2][t] + hp[3][t]) + bv[t];
    __syncthreads();

    // hid[l] = relu(b1[l] + sum_j z[j]*W1[j*128+l]); 4 segments x 128 j's
    {
        const int start = seg * 128;
        float v0 = 0.f, v1 = 0.f, v2 = 0.f, v3 = 0.f;
#pragma unroll 2
        for (int k = 0; k < 128; k += 4) {
            const int j = start + k;
            v0 += z[j]     * W1[(j)     * LL + l];
            v1 += z[j + 1] * W1[(j + 1) * LL + l];
            v2 += z[j + 2] * W1[(j + 2) * LL + l];
            v3 += z[j + 3] * W1[(j + 3) * LL + l];
        }
        hp[seg][l] = (v0 + v1) + (v2 + v3);
    }
    __syncthreads();
    if (t < LL)
        hid[t] = fmaxf((hp[0][t] + hp[1][t]) + (hp[2][t] + hp[3][t]) + b1[t], 0.f);
    __syncthreads();

    // out[l] = b2[l] + sum_j hid[j]*W2[j*128+l]; 4 segments x 32 j's
    {
        const int start = seg * 32;
        float v0 = 0.f, v1 = 0.f, v2 = 0.f, v3 = 0.f;
#pragma unroll
        for (int k = 0; k < 32; k += 4) {
            const int j = start + k;
            v0 += hid[j]     * W2[(j)     * LL + l];
            v1 += hid[j + 1] * W2[(j + 1) * LL + l];
            v2 += hid[j + 2] * W2[(j + 2) * LL + l];
            v3 += hid[j + 3] * W2[(j + 3) * LL + l];
        }
        hp[seg][l] = (v0 + v1) + (v2 + v3);
    }
    __syncthreads();
    if (t < LL)
        out[b * LL + t] = (hp[0][t] + hp[1][t]) + (hp[2][t] + hp[3][t]) + b2[t];
}

// ---------------------------------------------------------------------------
extern "C" void kernel_launch(void* const* d_in, const int* in_sizes, int n_in,
                              void* d_out, int out_size, void* d_ws, size_t ws_size,
                              hipStream_t stream)
{
    const float* target = (const float*)d_in[0];
    const float* h      = (const float*)d_in[1];
    const void*  mask   = d_in[2];
    const float* Wq = (const float*)d_in[3];
    const float* bq = (const float*)d_in[4];
    const float* Wk = (const float*)d_in[5];
    const float* bk = (const float*)d_in[6];
    const float* Wv = (const float*)d_in[7];
    const float* bv = (const float*)d_in[8];
    const float* W1 = (const float*)d_in[9];
    const float* b1 = (const float*)d_in[10];
    const float* W2 = (const float*)d_in[11];
    const float* b2 = (const float*)d_in[12];
    float* out = (float*)d_out;

    float* ws = (float*)d_ws;
    int*   flag = (int*)d_ws;
    float* u  = ws + 64;                  // 32*384
    float* c  = u + NB * DD;              // 32
    float* pm = c + NB;                   // 1024
    float* ps = pm + NB * CHUNKS;         // 1024
    float* pa = ps + NB * CHUNKS;         // 1024*384

    hipLaunchKernelGGL(ga_prep, dim3(NB), dim3(DD), 0, stream,
                       target, Wq, bq, Wk, bk, mask, u, c, flag);
    hipLaunchKernelGGL(ga_stream, dim3(NB * CHUNKS), dim3(256), 0, stream,
                       h, mask, u, c, flag, pm, ps, pa, Wv, W1, W2);
    hipLaunchKernelGGL(ga_finish, dim3(NB), dim3(512), 0, stream,
                       target, Wv, bv, W1, b1, W2, b2, pm, ps, pa, out);
}